// Round 16
// baseline (392.228 us; speedup 1.0000x reference)
//
#include <hip/hip_runtime.h>
#include <hip/hip_bf16.h>
#include <math.h>

#define S_LEN 2048
#define HID   4096
#define NQKV  6144
#define NHEAD 32
#define NKVH  8
#define HDIM  128

typedef __attribute__((ext_vector_type(8))) short short8;
typedef __attribute__((ext_vector_type(4))) float f32x4;

__device__ __forceinline__ unsigned short f2bf(float f) {
    union { float f; unsigned u; } v; v.f = f;
    unsigned r = v.u + 0x7fffu + ((v.u >> 16) & 1u);
    return (unsigned short)(r >> 16);
}
__device__ __forceinline__ float bf2f(unsigned short b) {
    union { unsigned u; float f; } v; v.u = ((unsigned)b) << 16;
    return v.f;
}
__device__ __forceinline__ unsigned cvt_pk_bf16(float lo, float hi) {
    unsigned r;
    asm("v_cvt_pk_bf16_f32 %0, %1, %2" : "=v"(r) : "v"(lo), "v"(hi));
    return r;
}

// radix-4 FWHT over LDS buf[4096]: 6 stages (4096 = 4^6).
__device__ __forceinline__ void fwht_lds_radix4(float* buf) {
    int lg = 0;
    for (int h = 1; h < HID; h <<= 2, lg += 2) {
        for (int p = threadIdx.x; p < HID / 4; p += 256) {
            int j  = p & (h - 1);
            int i0 = ((p >> lg) << (lg + 2)) | j;
            float a = buf[i0], b = buf[i0 + h], c = buf[i0 + 2 * h], d = buf[i0 + 3 * h];
            float apb = a + b, amb = a - b, cpd = c + d, cmd = c - d;
            buf[i0]         = apb + cpd;
            buf[i0 + h]     = amb + cmd;
            buf[i0 + 2 * h] = apb - cpd;
            buf[i0 + 3 * h] = amb - cmd;
        }
        __syncthreads();
    }
}

// ---------------- prep: FWHT(x) + scale-folded weight cvt --------------
__global__ __launch_bounds__(256)
void prep_kernel(const float* __restrict__ hidden, const float* __restrict__ su,
                 const float* __restrict__ ws_qkv, const float* __restrict__ ws_o,
                 const float* __restrict__ Wq, const float* __restrict__ Wk,
                 const float* __restrict__ Wv, const float* __restrict__ Wo,
                 unsigned short* __restrict__ xb, unsigned short* __restrict__ Wcat,
                 unsigned short* __restrict__ Wob) {
    __shared__ float buf[HID];
    int b = blockIdx.x;
    if (b < S_LEN) {                 // FWHT
        const float* src = hidden + (size_t)b * HID;
        for (int i = threadIdx.x; i < HID; i += 256) buf[i] = src[i] * su[i];
        __syncthreads();
        fwht_lds_radix4(buf);
        unsigned short* dst = xb + (size_t)b * HID;
        const float norm = 1.0f / 4096.0f;
        for (int i = threadIdx.x; i < HID; i += 256) dst[i] = f2bf(buf[i] * norm);
        return;
    }
    b -= S_LEN;
    {                                // weight cvt with folded scales
        const int NQ = 4194304, NK = 1048576, NV = 1048576, NO = 4194304; // float4 counts
        const float QS = 0.12751793f;   // (1/sqrt(128)) * log2(e)
        int i = b * 256 + threadIdx.x;
        const int stride = 2560 * 256;
        for (; i < NQ + NK + NV + NO; i += stride) {
            const float* src; unsigned short* dst; int j; float sc;
            if (i < NQ)                { src = Wq; dst = Wcat;            j = i;
                                         sc = ws_qkv[j >> 10] * 64.0f * QS; }
            else if (i < NQ + NK)      { src = Wk; dst = Wcat + 16777216; j = i - NQ;
                                         sc = ws_qkv[4096 + (j >> 10)] * 64.0f; }
            else if (i < NQ + NK + NV) { src = Wv; dst = Wcat + 20971520; j = i - NQ - NK;
                                         sc = ws_qkv[5120 + (j >> 10)] * 64.0f; }
            else                       { src = Wo; dst = Wob;             j = i - NQ - NK - NV;
                                         sc = ws_o[j >> 10] * 64.0f; }
            float4 v = *(const float4*)(src + (size_t)j * 4);
            ushort4 o;
            o.x = f2bf(v.x * sc); o.y = f2bf(v.y * sc);
            o.z = f2bf(v.z * sc); o.w = f2bf(v.w * sc);
            *(ushort4*)(dst + (size_t)j * 4) = o;
        }
    }
}

// ---------------- merge 2 split-KV partials + FWHT + *su/4096 -> bf16 ----------------
__global__ __launch_bounds__(256)
void fwht_merge(const unsigned short* __restrict__ O1, const float* __restrict__ ML,
                const float* __restrict__ su, unsigned short* __restrict__ out) {
    __shared__ float buf[HID];
    __shared__ float w1s[NHEAD], w2s[NHEAD];
    const int q = blockIdx.x;
    if (threadIdx.x < NHEAD) {
        const float2* mlp = (const float2*)ML;
        float2 a = mlp[((size_t)q) * NHEAD + threadIdx.x];
        float2 b = mlp[((size_t)(S_LEN + q)) * NHEAD + threadIdx.x];
        float M = fmaxf(a.x, b.x);
        float e1 = exp2f(a.x - M), e2 = exp2f(b.x - M);
        float L = e1 * a.y + e2 * b.y;
        w1s[threadIdx.x] = e1 / L;
        w2s[threadIdx.x] = e2 / L;
    }
    __syncthreads();
    const unsigned short* r1 = O1 + (size_t)q * HID;
    const unsigned short* r2 = O1 + (size_t)(S_LEN + q) * HID;
    for (int i = threadIdx.x; i < HID; i += 256) {
        int hd = i >> 7;
        buf[i] = (bf2f(r1[i]) * w1s[hd] + bf2f(r2[i]) * w2s[hd]) * su[i];
    }
    __syncthreads();
    fwht_lds_radix4(buf);
    unsigned short* dst = out + (size_t)q * HID;
    const float norm = 1.0f / 4096.0f;
    for (int i = threadIdx.x; i < HID; i += 256) dst[i] = f2bf(buf[i] * norm);
}

// ---------------- bf16 GEMM (m97 + swizzle + XCD-chunked remap) for O-proj ----------
// 1D grid 512: wg = (id&7)*64 + id>>3 -> each XCD owns 2 bm-rows x all bn:
// A-panels (2MB) L2-resident; co-resident (bm0,bn),(bm1,bn) share B-panel fetch.
__global__ __launch_bounds__(256)
void gemm_bt(const unsigned short* __restrict__ A, const unsigned short* __restrict__ B,
             float* __restrict__ C, int M, int N, int K) {
    __shared__ __attribute__((aligned(16))) unsigned short As[2][128 * 32];
    __shared__ __attribute__((aligned(16))) unsigned short Bs[2][128 * 32];
    const int id = blockIdx.x;
    const int wg = (id & 7) * 64 + (id >> 3);   // nwg=512, chunk=64
    const int bn = wg % 32, bm = wg / 32;
    const int tid = threadIdx.x;
    const int wv = tid >> 6, lane = tid & 63;
    const int wr = wv >> 1, wc = wv & 1;
    const int lr = lane & 15, lgp = lane >> 4;

    f32x4 acc[4][4] = {};

    auto stage = [&](int buf, int kt) {
        for (int c = wv; c < 8; c += 4) {
            int o = c * 512 + lane * 8;
            int row = o >> 5;
            int col = (o & 31) ^ (((o >> 6) & 3) << 3);   // inverse-swizzled source col
            const unsigned short* ga = A + (size_t)(bm * 128 + row) * K + kt * 32 + col;
            __builtin_amdgcn_global_load_lds((const __attribute__((address_space(1))) void*)ga,
                (__attribute__((address_space(3))) void*)&As[buf][c * 512], 16, 0, 0);
            const unsigned short* gb = B + (size_t)(bn * 128 + row) * K + kt * 32 + col;
            __builtin_amdgcn_global_load_lds((const __attribute__((address_space(1))) void*)gb,
                (__attribute__((address_space(3))) void*)&Bs[buf][c * 512], 16, 0, 0);
        }
    };

    const int nt = K >> 5;
    stage(0, 0);
    __syncthreads();
    int cur = 0;
    for (int kt = 0; kt < nt; ++kt) {
        if (kt + 1 < nt) stage(cur ^ 1, kt + 1);
        short8 af[4], bfr[4];
#pragma unroll
        for (int m2 = 0; m2 < 4; ++m2) {
            int row = wr * 64 + m2 * 16 + lr;
            af[m2] = *(const short8*)&As[cur][row * 32 + (lgp * 8 ^ (((row >> 1) & 3) << 3))];
        }
#pragma unroll
        for (int n2 = 0; n2 < 4; ++n2) {
            int row = wc * 64 + n2 * 16 + lr;
            bfr[n2] = *(const short8*)&Bs[cur][row * 32 + (lgp * 8 ^ (((row >> 1) & 3) << 3))];
        }
#pragma unroll
        for (int m2 = 0; m2 < 4; ++m2)
#pragma unroll
            for (int n2 = 0; n2 < 4; ++n2)
                acc[m2][n2] = __builtin_amdgcn_mfma_f32_16x16x32_bf16(af[m2], bfr[n2], acc[m2][n2], 0, 0, 0);
        __syncthreads();
        cur ^= 1;
    }

#pragma unroll
    for (int n2 = 0; n2 < 4; ++n2) {
        int gn = bn * 128 + wc * 64 + n2 * 16 + lr;
#pragma unroll
        for (int m2 = 0; m2 < 4; ++m2) {
            int gm0 = bm * 128 + wr * 64 + m2 * 16 + lgp * 4;
#pragma unroll
            for (int i = 0; i < 4; ++i)
                C[(size_t)(gm0 + i) * N + gn] = acc[m2][n2][i];
        }
    }
}

// ---------------- QKV GEMM: folded scales; sincosf RoPE; swizzle; XCD-chunked -------
__global__ __launch_bounds__(256)
void gemm_qkv(const unsigned short* __restrict__ A, const unsigned short* __restrict__ B,
              const int* __restrict__ pos,
              unsigned short* __restrict__ Qb, unsigned short* __restrict__ Kb,
              unsigned short* __restrict__ Vb) {
    const int K = HID;
    __shared__ __attribute__((aligned(16))) unsigned short As[2][128 * 32];
    __shared__ __attribute__((aligned(16))) unsigned short Bs[2][128 * 32];
    __shared__ float invf_t[64];
    __shared__ float poss[128];
    const int id = blockIdx.x;
    const int wg = (id & 7) * 96 + (id >> 3);   // nwg=768, chunk=96
    const int bn = wg % 48, bm = wg / 48;
    const int tid = threadIdx.x;
    const int wv = tid >> 6, lane = tid & 63;
    const int wr = wv >> 1, wc = wv & 1;
    const int lr = lane & 15, lgp = lane >> 4;

    if (tid < 64) invf_t[tid] = exp2f((float)tid * -0.29580576f); // theta^(-j/64)
    if (tid >= 128) poss[tid - 128] = (float)pos[bm * 128 + (tid - 128)];

    f32x4 acc[4][4] = {};

    auto stage = [&](int buf, int kt) {
        for (int c = wv; c < 8; c += 4) {
            int o = c * 512 + lane * 8;
            int row = o >> 5;
            int col = (o & 31) ^ (((o >> 6) & 3) << 3);   // inverse-swizzled source col
            const unsigned short* ga = A + (size_t)(bm * 128 + row) * K + kt * 32 + col;
            __builtin_amdgcn_global_load_lds((const __attribute__((address_space(1))) void*)ga,
                (__attribute__((address_space(3))) void*)&As[buf][c * 512], 16, 0, 0);
            int prow = (row & 31) | ((row & 32) << 1) | ((row & 64) >> 1); // swap bits 5<->6
            const unsigned short* gb = B + (size_t)(bn * 128 + prow) * K + kt * 32 + col;
            __builtin_amdgcn_global_load_lds((const __attribute__((address_space(1))) void*)gb,
                (__attribute__((address_space(3))) void*)&Bs[buf][c * 512], 16, 0, 0);
        }
    };

    const int nt = K >> 5;
    stage(0, 0);
    __syncthreads();
    int cur = 0;
    for (int kt = 0; kt < nt; ++kt) {
        if (kt + 1 < nt) stage(cur ^ 1, kt + 1);
        short8 af[4], bfr[4];
#pragma unroll
        for (int m2 = 0; m2 < 4; ++m2) {
            int row = wr * 64 + m2 * 16 + lr;
            af[m2] = *(const short8*)&As[cur][row * 32 + (lgp * 8 ^ (((row >> 1) & 3) << 3))];
        }
#pragma unroll
        for (int n2 = 0; n2 < 4; ++n2) {
            int row = wc * 64 + n2 * 16 + lr;
            bfr[n2] = *(const short8*)&Bs[cur][row * 32 + (lgp * 8 ^ (((row >> 1) & 3) << 3))];
        }
#pragma unroll
        for (int m2 = 0; m2 < 4; ++m2)
#pragma unroll
            for (int n2 = 0; n2 < 4; ++n2)
                acc[m2][n2] = __builtin_amdgcn_mfma_f32_16x16x32_bf16(af[m2], bfr[n2], acc[m2][n2], 0, 0, 0);
        __syncthreads();
        cur ^= 1;
    }

    // epilogue: d = (n2&1)*16 + lr + wc*32 (+64 for the hi half); scales already in W
#pragma unroll
    for (int n2 = 0; n2 < 2; ++n2) {
        const int d = n2 * 16 + lr + wc * 32;      // 0..63, j = d
        const float ivf = invf_t[d];
#pragma unroll
        for (int m2 = 0; m2 < 4; ++m2) {
#pragma unroll
            for (int i = 0; i < 4; ++i) {
                const int lrow = wr * 64 + m2 * 16 + lgp * 4 + i;
                const int srow = bm * 128 + lrow;
                float lo = acc[m2][n2][i];
                float hi = acc[m2][n2 + 2][i];
                float olo, ohi;
                if (bn < 40) {
                    float sn, cs;
                    sincosf(poss[lrow] * ivf, &sn, &cs);
                    olo = lo * cs - hi * sn;
                    ohi = hi * cs + lo * sn;
                } else { olo = lo; ohi = hi; }
                unsigned short* dst;
                if (bn < 32)      dst = Qb + ((size_t)bn * S_LEN + srow) * HDIM;
                else if (bn < 40) dst = Kb + ((size_t)(bn - 32) * S_LEN + srow) * HDIM;
                else              dst = Vb + ((size_t)(bn - 40) * S_LEN + srow) * HDIM;
                dst[d]      = f2bf(olo);
                dst[d + 64] = f2bf(ohi);
            }
        }
    }
}

// ---------------- causal GQA flash attention, 2-way split-KV, 128-row q-tiles -------
__global__ __launch_bounds__(512)
void attn_kernel(const unsigned short* __restrict__ Q, const unsigned short* __restrict__ K,
                 const unsigned short* __restrict__ V, unsigned short* __restrict__ Opart,
                 float* __restrict__ ML) {
    const int hf = blockIdx.y;
    const int hd = blockIdx.z;
    const int kvh = hd >> 2;
    const int tid = threadIdx.x, wv = tid >> 6, lane = tid & 63;
    const int lr = lane & 15, lgp = lane >> 4;

    __shared__ __attribute__((aligned(16))) unsigned short Ks[2][64 * 128];
    __shared__ __attribute__((aligned(16))) unsigned short Vt[128 * 64];

    int koff[2];
#pragma unroll
    for (int j = 0; j < 2; ++j) {
        int a = (wv * 2 + j) * 512 + lane * 8;
        koff[j] = a ^ (((a >> 7) & 7) << 3);
    }
    const int vpos = ((lane >> 2) & 3) * 16 + (lane >> 4) * 4 + (lane & 3);
    const unsigned short* Kg = K + (size_t)kvh * S_LEN * HDIM;
    const unsigned short* Vg = V + (size_t)kvh * S_LEN * HDIM;

    auto stageK = [&](int buf, int kb) {
        const unsigned short* kg = Kg + (size_t)kb * 64 * HDIM;
#pragma unroll
        for (int j = 0; j < 2; ++j) {
            __builtin_amdgcn_global_load_lds(
                (const __attribute__((address_space(1))) void*)(kg + koff[j]),
                (__attribute__((address_space(3))) void*)&Ks[buf][(wv * 2 + j) * 512], 16, 0, 0);
        }
    };

#pragma unroll 1
    for (int rep = 0; rep < 2; ++rep) {
        const int qt = rep ? (15 - (int)blockIdx.x) : (int)blockIdx.x;  // 128-row tile
        const int qg = qt * 128 + wv * 16 + lr;
        const int n = 2 * qt + 2, mid = qt + 1;
        const int s = hf ? mid : 0, e = hf ? n : mid;

        __syncthreads();   // LDS reuse guard across reps

        short8 aq[4];
        {
            const unsigned short* qp = Q + ((size_t)hd * S_LEN + qg) * HDIM + lgp * 8;
#pragma unroll
            for (int kk = 0; kk < 4; ++kk) aq[kk] = *(const short8*)(qp + kk * 32);
        }

        f32x4 oacc[8] = {};
        float m_i = -3.0e38f, l_i = 0.f;

        short8 vcur[2];
        if (s < e) {
            stageK(s & 1, s);
            const unsigned short* vp = Vg + (size_t)s * 64 * HDIM + lane * HDIM + wv * 16;
#pragma unroll
            for (int r2 = 0; r2 < 2; ++r2) vcur[r2] = *(const short8*)(vp + r2 * 8);
        }

#pragma unroll 1
        for (int kb = s; kb < e; ++kb) {
            const int cur = kb & 1;
            __syncthreads();   // b1: drains prev-iter stage + V loads; prev PV done

            if (kb + 1 < e) stageK(cur ^ 1, kb + 1);
#pragma unroll
            for (int r2 = 0; r2 < 2; ++r2) {
#pragma unroll
                for (int en = 0; en < 8; ++en) {
                    int d = wv * 16 + r2 * 8 + en;
                    Vt[(d * 64 + vpos) ^ ((d & 7) << 3)] = ((const unsigned short*)&vcur[r2])[en];
                }
            }
            if (kb + 1 < e) {
                const unsigned short* vp = Vg + (size_t)(kb + 1) * 64 * HDIM + lane * HDIM + wv * 16;
#pragma unroll
                for (int r2 = 0; r2 < 2; ++r2) vcur[r2] = *(const short8*)(vp + r2 * 8);
            }

            __builtin_amdgcn_s_setprio(1);
            f32x4 sc[4];
#pragma unroll
            for (int nt2 = 0; nt2 < 4; ++nt2) {
                f32x4 a = {};
                const int krow = nt2 * 16 + lr;
                const int swz = (krow & 7) << 3;
#pragma unroll
                for (int kk = 0; kk < 4; ++kk) {
                    short8 ak = *(const short8*)&Ks[cur][(krow * 128 + kk * 32 + lgp * 8) ^ swz];
                    a = __builtin_amdgcn_mfma_f32_16x16x32_bf16(ak, aq[kk], a, 0, 0, 0);
                }
                sc[nt2] = a;
            }
            __builtin_amdgcn_s_setprio(0);

            if (kb >= 2 * qt) {   // diagonal kv tiles of this 128-row q-tile
#pragma unroll
                for (int nt2 = 0; nt2 < 4; ++nt2)
#pragma unroll
                    for (int i = 0; i < 4; ++i) {
                        int kvg = kb * 64 + nt2 * 16 + 4 * lgp + i;
                        if (kvg > qg) sc[nt2][i] = -1.0e30f;
                    }
            }

            float vmax = fmaxf(fmaxf(fmaxf(sc[0][0], sc[0][1]), fmaxf(sc[0][2], sc[0][3])),
                               fmaxf(fmaxf(sc[1][0], sc[1][1]), fmaxf(sc[1][2], sc[1][3])));
            vmax = fmaxf(vmax, fmaxf(fmaxf(fmaxf(sc[2][0], sc[2][1]), fmaxf(sc[2][2], sc[2][3])),
                                     fmaxf(fmaxf(sc[3][0], sc[3][1]), fmaxf(sc[3][2], sc[3][3]))));
            vmax = fmaxf(vmax, __shfl_xor(vmax, 16));
            vmax = fmaxf(vmax, __shfl_xor(vmax, 32));

            if (!__all(vmax <= m_i + 11.0f)) {   // defer-max: P bounded by 2^11
                float mn = fmaxf(m_i, vmax);
                float fe = __builtin_amdgcn_exp2f(m_i - mn);
                m_i = mn;
                l_i *= fe;
                float feb[4];
#pragma unroll
                for (int i2 = 0; i2 < 4; ++i2) feb[i2] = __shfl(fe, 4 * lgp + i2);
#pragma unroll
                for (int t = 0; t < 8; ++t)
#pragma unroll
                    for (int i2 = 0; i2 < 4; ++i2) oacc[t][i2] *= feb[i2];
            }

            float rs = 0.f;
#pragma unroll
            for (int nt2 = 0; nt2 < 4; ++nt2)
#pragma unroll
                for (int i = 0; i < 4; ++i) {
                    float pv = __builtin_amdgcn_exp2f(sc[nt2][i] - m_i);
                    sc[nt2][i] = pv;
                    rs += pv;
                }
            rs += __shfl_xor(rs, 16);
            rs += __shfl_xor(rs, 32);
            l_i += rs;

            union { unsigned u[4]; short8 sv; } a0, a1;
            a0.u[0] = cvt_pk_bf16(sc[0][0], sc[0][1]);
            a0.u[1] = cvt_pk_bf16(sc[0][2], sc[0][3]);
            a0.u[2] = cvt_pk_bf16(sc[1][0], sc[1][1]);
            a0.u[3] = cvt_pk_bf16(sc[1][2], sc[1][3]);
            a1.u[0] = cvt_pk_bf16(sc[2][0], sc[2][1]);
            a1.u[1] = cvt_pk_bf16(sc[2][2], sc[2][3]);
            a1.u[2] = cvt_pk_bf16(sc[3][0], sc[3][1]);
            a1.u[3] = cvt_pk_bf16(sc[3][2], sc[3][3]);

            // b2: scatter visibility only — NO vmcnt drain (staging keeps flying)
            asm volatile("s_waitcnt lgkmcnt(0)" ::: "memory");
            __builtin_amdgcn_sched_barrier(0);
            __builtin_amdgcn_s_barrier();

            __builtin_amdgcn_s_setprio(1);
#pragma unroll
            for (int t = 0; t < 8; ++t) {
                const int d = t * 16 + lr;
                const int swz = (d & 7) << 3;
                const int dbase = d * 64 + lgp * 16;
                short8 bv0 = *(const short8*)&Vt[(dbase) ^ swz];
                short8 bv1 = *(const short8*)&Vt[(dbase + 8) ^ swz];
                oacc[t] = __builtin_amdgcn_mfma_f32_16x16x32_bf16(a0.sv, bv0, oacc[t], 0, 0, 0);
                oacc[t] = __builtin_amdgcn_mfma_f32_16x16x32_bf16(a1.sv, bv1, oacc[t], 0, 0, 0);
            }
            __builtin_amdgcn_s_setprio(0);
        }

        unsigned short* op = Opart + ((size_t)hf * S_LEN + qt * 128 + wv * 16 + 4 * lgp) * HID
                           + hd * HDIM + lr;
#pragma unroll
        for (int t = 0; t < 8; ++t)
#pragma unroll
            for (int i2 = 0; i2 < 4; ++i2)
                op[(size_t)i2 * HID + t * 16] = f2bf(oacc[t][i2]);
        if (lgp == 0) {
            float2* mlp = (float2*)ML;
            mlp[((size_t)hf * S_LEN + qt * 128 + wv * 16 + lr) * NHEAD + hd] =
                make_float2(m_i, l_i);
        }
    }
}

// ---------------- launch ----------------
extern "C" void kernel_launch(void* const* d_in, const int* in_sizes, int n_in,
                              void* d_out, int out_size, void* d_ws, size_t ws_size,
                              hipStream_t stream) {
    const float* hidden = (const float*)d_in[0];
    const int*   pos    = (const int*)d_in[1];
    const float* su_qkv = (const float*)d_in[2];
    const float* su_o   = (const float*)d_in[3];
    const float* ws_qkv = (const float*)d_in[4];
    const float* ws_o   = (const float*)d_in[5];
    const float* Wq     = (const float*)d_in[6];
    const float* Wk     = (const float*)d_in[7];
    const float* Wv     = (const float*)d_in[8];
    const float* Wo     = (const float*)d_in[9];
    float* out = (float*)d_out;

    char* ws = (char*)d_ws;
    unsigned short* Wcat = (unsigned short*)(ws);                        // [6144][4096] bf16
    unsigned short* Wob  = (unsigned short*)(ws + 50331648);             // [4096][4096] bf16
    unsigned short* xb   = (unsigned short*)(ws + 83886080);             // [2048][4096] bf16
    unsigned short* Opart= (unsigned short*)(ws + 100663296);            // [2][2048][4096] bf16
    float*          ML   = (float*)(ws + 134217728);                     // [2][2048][32][2] f32
    unsigned short* Qb   = (unsigned short*)(ws + 150994944);            // [32][2048][128] bf16
    unsigned short* Kb   = Qb + (size_t)NHEAD * S_LEN * HDIM;
    unsigned short* Vb   = Kb + (size_t)NKVH * S_LEN * HDIM;

    prep_kernel<<<4608, 256, 0, stream>>>(hidden, su_qkv, ws_qkv, ws_o,
                                          Wq, Wk, Wv, Wo, xb, Wcat, Wob);
    gemm_qkv<<<768, 256, 0, stream>>>(xb, Wcat, pos, Qb, Kb, Vb);
    attn_kernel<<<dim3(8, 2, NHEAD), 512, 0, stream>>>(Qb, Kb, Vb, Opart, ML);
    fwht_merge<<<S_LEN, 256, 0, stream>>>(Opart, ML, su_o, xb);
    gemm_bt<<<512, 256, 0, stream>>>(xb, Wob, out, S_LEN, HID, HID);
}

// Round 17
// 386.179 us; speedup vs baseline: 1.0157x; 1.0157x over previous
//
#include <hip/hip_runtime.h>
#include <hip/hip_bf16.h>
#include <math.h>

#define S_LEN 2048
#define HID   4096
#define NQKV  6144
#define NHEAD 32
#define NKVH  8
#define HDIM  128

typedef __attribute__((ext_vector_type(8))) short short8;
typedef __attribute__((ext_vector_type(4))) float f32x4;

__device__ __forceinline__ unsigned short f2bf(float f) {
    union { float f; unsigned u; } v; v.f = f;
    unsigned r = v.u + 0x7fffu + ((v.u >> 16) & 1u);
    return (unsigned short)(r >> 16);
}
__device__ __forceinline__ float bf2f(unsigned short b) {
    union { unsigned u; float f; } v; v.u = ((unsigned)b) << 16;
    return v.f;
}
__device__ __forceinline__ unsigned cvt_pk_bf16(float lo, float hi) {
    unsigned r;
    asm("v_cvt_pk_bf16_f32 %0, %1, %2" : "=v"(r) : "v"(lo), "v"(hi));
    return r;
}

// radix-4 FWHT over LDS buf[4096]: 6 stages (4096 = 4^6).
__device__ __forceinline__ void fwht_lds_radix4(float* buf) {
    int lg = 0;
    for (int h = 1; h < HID; h <<= 2, lg += 2) {
        for (int p = threadIdx.x; p < HID / 4; p += 256) {
            int j  = p & (h - 1);
            int i0 = ((p >> lg) << (lg + 2)) | j;
            float a = buf[i0], b = buf[i0 + h], c = buf[i0 + 2 * h], d = buf[i0 + 3 * h];
            float apb = a + b, amb = a - b, cpd = c + d, cmd = c - d;
            buf[i0]         = apb + cpd;
            buf[i0 + h]     = amb + cmd;
            buf[i0 + 2 * h] = apb - cpd;
            buf[i0 + 3 * h] = amb - cmd;
        }
        __syncthreads();
    }
}

// ---------------- prep: FWHT(x) + scale-folded weight cvt --------------
__global__ __launch_bounds__(256)
void prep_kernel(const float* __restrict__ hidden, const float* __restrict__ su,
                 const float* __restrict__ ws_qkv, const float* __restrict__ ws_o,
                 const float* __restrict__ Wq, const float* __restrict__ Wk,
                 const float* __restrict__ Wv, const float* __restrict__ Wo,
                 unsigned short* __restrict__ xb, unsigned short* __restrict__ Wcat,
                 unsigned short* __restrict__ Wob) {
    __shared__ float buf[HID];
    int b = blockIdx.x;
    if (b < S_LEN) {                 // FWHT
        const float* src = hidden + (size_t)b * HID;
        for (int i = threadIdx.x; i < HID; i += 256) buf[i] = src[i] * su[i];
        __syncthreads();
        fwht_lds_radix4(buf);
        unsigned short* dst = xb + (size_t)b * HID;
        const float norm = 1.0f / 4096.0f;
        for (int i = threadIdx.x; i < HID; i += 256) dst[i] = f2bf(buf[i] * norm);
        return;
    }
    b -= S_LEN;
    {                                // weight cvt with folded scales
        const int NQ = 4194304, NK = 1048576, NV = 1048576, NO = 4194304; // float4 counts
        const float QS = 0.12751793f;   // (1/sqrt(128)) * log2(e)
        int i = b * 256 + threadIdx.x;
        const int stride = 2560 * 256;
        for (; i < NQ + NK + NV + NO; i += stride) {
            const float* src; unsigned short* dst; int j; float sc;
            if (i < NQ)                { src = Wq; dst = Wcat;            j = i;
                                         sc = ws_qkv[j >> 10] * 64.0f * QS; }
            else if (i < NQ + NK)      { src = Wk; dst = Wcat + 16777216; j = i - NQ;
                                         sc = ws_qkv[4096 + (j >> 10)] * 64.0f; }
            else if (i < NQ + NK + NV) { src = Wv; dst = Wcat + 20971520; j = i - NQ - NK;
                                         sc = ws_qkv[5120 + (j >> 10)] * 64.0f; }
            else                       { src = Wo; dst = Wob;             j = i - NQ - NK - NV;
                                         sc = ws_o[j >> 10] * 64.0f; }
            float4 v = *(const float4*)(src + (size_t)j * 4);
            ushort4 o;
            o.x = f2bf(v.x * sc); o.y = f2bf(v.y * sc);
            o.z = f2bf(v.z * sc); o.w = f2bf(v.w * sc);
            *(ushort4*)(dst + (size_t)j * 4) = o;
        }
    }
}

// ---------------- merge 2 split-KV partials + FWHT + *su/4096 -> bf16 ----------------
__global__ __launch_bounds__(256)
void fwht_merge(const unsigned short* __restrict__ O1, const float* __restrict__ ML,
                const float* __restrict__ su, unsigned short* __restrict__ out) {
    __shared__ float buf[HID];
    __shared__ float w1s[NHEAD], w2s[NHEAD];
    const int q = blockIdx.x;
    if (threadIdx.x < NHEAD) {
        const float2* mlp = (const float2*)ML;
        float2 a = mlp[((size_t)q) * NHEAD + threadIdx.x];
        float2 b = mlp[((size_t)(S_LEN + q)) * NHEAD + threadIdx.x];
        float M = fmaxf(a.x, b.x);
        float e1 = exp2f(a.x - M), e2 = exp2f(b.x - M);
        float L = e1 * a.y + e2 * b.y;
        w1s[threadIdx.x] = e1 / L;
        w2s[threadIdx.x] = e2 / L;
    }
    __syncthreads();
    const unsigned short* r1 = O1 + (size_t)q * HID;
    const unsigned short* r2 = O1 + (size_t)(S_LEN + q) * HID;
    for (int i = threadIdx.x; i < HID; i += 256) {
        int hd = i >> 7;
        buf[i] = (bf2f(r1[i]) * w1s[hd] + bf2f(r2[i]) * w2s[hd]) * su[i];
    }
    __syncthreads();
    fwht_lds_radix4(buf);
    unsigned short* dst = out + (size_t)q * HID;
    const float norm = 1.0f / 4096.0f;
    for (int i = threadIdx.x; i < HID; i += 256) dst[i] = f2bf(buf[i] * norm);
}

// ---------------- bf16 GEMM (m97 structure + LDS XOR-swizzle) for O-proj ------------
__global__ __launch_bounds__(256)
void gemm_bt(const unsigned short* __restrict__ A, const unsigned short* __restrict__ B,
             float* __restrict__ C, int M, int N, int K) {
    __shared__ __attribute__((aligned(16))) unsigned short As[2][128 * 32];
    __shared__ __attribute__((aligned(16))) unsigned short Bs[2][128 * 32];
    const int bn = blockIdx.x, bm = blockIdx.y;
    const int tid = threadIdx.x;
    const int wv = tid >> 6, lane = tid & 63;
    const int wr = wv >> 1, wc = wv & 1;
    const int lr = lane & 15, lgp = lane >> 4;

    f32x4 acc[4][4] = {};

    auto stage = [&](int buf, int kt) {
        for (int c = wv; c < 8; c += 4) {
            int o = c * 512 + lane * 8;
            int row = o >> 5;
            int col = (o & 31) ^ (((o >> 6) & 3) << 3);   // inverse-swizzled source col
            const unsigned short* ga = A + (size_t)(bm * 128 + row) * K + kt * 32 + col;
            __builtin_amdgcn_global_load_lds((const __attribute__((address_space(1))) void*)ga,
                (__attribute__((address_space(3))) void*)&As[buf][c * 512], 16, 0, 0);
            const unsigned short* gb = B + (size_t)(bn * 128 + row) * K + kt * 32 + col;
            __builtin_amdgcn_global_load_lds((const __attribute__((address_space(1))) void*)gb,
                (__attribute__((address_space(3))) void*)&Bs[buf][c * 512], 16, 0, 0);
        }
    };

    const int nt = K >> 5;
    stage(0, 0);
    __syncthreads();
    int cur = 0;
    for (int kt = 0; kt < nt; ++kt) {
        if (kt + 1 < nt) stage(cur ^ 1, kt + 1);
        short8 af[4], bfr[4];
#pragma unroll
        for (int m2 = 0; m2 < 4; ++m2) {
            int row = wr * 64 + m2 * 16 + lr;
            af[m2] = *(const short8*)&As[cur][row * 32 + (lgp * 8 ^ (((row >> 1) & 3) << 3))];
        }
#pragma unroll
        for (int n2 = 0; n2 < 4; ++n2) {
            int row = wc * 64 + n2 * 16 + lr;
            bfr[n2] = *(const short8*)&Bs[cur][row * 32 + (lgp * 8 ^ (((row >> 1) & 3) << 3))];
        }
#pragma unroll
        for (int m2 = 0; m2 < 4; ++m2)
#pragma unroll
            for (int n2 = 0; n2 < 4; ++n2)
                acc[m2][n2] = __builtin_amdgcn_mfma_f32_16x16x32_bf16(af[m2], bfr[n2], acc[m2][n2], 0, 0, 0);
        __syncthreads();
        cur ^= 1;
    }

#pragma unroll
    for (int n2 = 0; n2 < 4; ++n2) {
        int gn = bn * 128 + wc * 64 + n2 * 16 + lr;
#pragma unroll
        for (int m2 = 0; m2 < 4; ++m2) {
            int gm0 = bm * 128 + wr * 64 + m2 * 16 + lgp * 4;
#pragma unroll
            for (int i = 0; i < 4; ++i)
                C[(size_t)(gm0 + i) * N + gn] = acc[m2][n2][i];
        }
    }
}

// ---------------- QKV GEMM: scales pre-folded; RoPE sincosf; LDS XOR-swizzle --------
__global__ __launch_bounds__(256)
void gemm_qkv(const unsigned short* __restrict__ A, const unsigned short* __restrict__ B,
              const int* __restrict__ pos,
              unsigned short* __restrict__ Qb, unsigned short* __restrict__ Kb,
              unsigned short* __restrict__ Vb) {
    const int K = HID;
    __shared__ __attribute__((aligned(16))) unsigned short As[2][128 * 32];
    __shared__ __attribute__((aligned(16))) unsigned short Bs[2][128 * 32];
    __shared__ float invf_t[64];
    __shared__ float poss[128];
    const int bn = blockIdx.x, bm = blockIdx.y;
    const int tid = threadIdx.x;
    const int wv = tid >> 6, lane = tid & 63;
    const int wr = wv >> 1, wc = wv & 1;
    const int lr = lane & 15, lgp = lane >> 4;

    if (tid < 64) invf_t[tid] = exp2f((float)tid * -0.29580576f); // theta^(-j/64)
    if (tid >= 128) poss[tid - 128] = (float)pos[bm * 128 + (tid - 128)];

    f32x4 acc[4][4] = {};

    auto stage = [&](int buf, int kt) {
        for (int c = wv; c < 8; c += 4) {
            int o = c * 512 + lane * 8;
            int row = o >> 5;
            int col = (o & 31) ^ (((o >> 6) & 3) << 3);   // inverse-swizzled source col
            const unsigned short* ga = A + (size_t)(bm * 128 + row) * K + kt * 32 + col;
            __builtin_amdgcn_global_load_lds((const __attribute__((address_space(1))) void*)ga,
                (__attribute__((address_space(3))) void*)&As[buf][c * 512], 16, 0, 0);
            int prow = (row & 31) | ((row & 32) << 1) | ((row & 64) >> 1); // swap bits 5<->6
            const unsigned short* gb = B + (size_t)(bn * 128 + prow) * K + kt * 32 + col;
            __builtin_amdgcn_global_load_lds((const __attribute__((address_space(1))) void*)gb,
                (__attribute__((address_space(3))) void*)&Bs[buf][c * 512], 16, 0, 0);
        }
    };

    const int nt = K >> 5;
    stage(0, 0);
    __syncthreads();
    int cur = 0;
    for (int kt = 0; kt < nt; ++kt) {
        if (kt + 1 < nt) stage(cur ^ 1, kt + 1);
        short8 af[4], bfr[4];
#pragma unroll
        for (int m2 = 0; m2 < 4; ++m2) {
            int row = wr * 64 + m2 * 16 + lr;
            af[m2] = *(const short8*)&As[cur][row * 32 + (lgp * 8 ^ (((row >> 1) & 3) << 3))];
        }
#pragma unroll
        for (int n2 = 0; n2 < 4; ++n2) {
            int row = wc * 64 + n2 * 16 + lr;
            bfr[n2] = *(const short8*)&Bs[cur][row * 32 + (lgp * 8 ^ (((row >> 1) & 3) << 3))];
        }
#pragma unroll
        for (int m2 = 0; m2 < 4; ++m2)
#pragma unroll
            for (int n2 = 0; n2 < 4; ++n2)
                acc[m2][n2] = __builtin_amdgcn_mfma_f32_16x16x32_bf16(af[m2], bfr[n2], acc[m2][n2], 0, 0, 0);
        __syncthreads();
        cur ^= 1;
    }

    // epilogue: d = (n2&1)*16 + lr + wc*32 (+64 for the hi half); scales already in W
#pragma unroll
    for (int n2 = 0; n2 < 2; ++n2) {
        const int d = n2 * 16 + lr + wc * 32;      // 0..63, j = d
        const float ivf = invf_t[d];
#pragma unroll
        for (int m2 = 0; m2 < 4; ++m2) {
#pragma unroll
            for (int i = 0; i < 4; ++i) {
                const int lrow = wr * 64 + m2 * 16 + lgp * 4 + i;
                const int srow = bm * 128 + lrow;
                float lo = acc[m2][n2][i];
                float hi = acc[m2][n2 + 2][i];
                float olo, ohi;
                if (bn < 40) {
                    float sn, cs;
                    sincosf(poss[lrow] * ivf, &sn, &cs);
                    olo = lo * cs - hi * sn;
                    ohi = hi * cs + lo * sn;
                } else { olo = lo; ohi = hi; }
                unsigned short* dst;
                if (bn < 32)      dst = Qb + ((size_t)bn * S_LEN + srow) * HDIM;
                else if (bn < 40) dst = Kb + ((size_t)(bn - 32) * S_LEN + srow) * HDIM;
                else              dst = Vb + ((size_t)(bn - 40) * S_LEN + srow) * HDIM;
                dst[d]      = f2bf(olo);
                dst[d + 64] = f2bf(ohi);
            }
        }
    }
}

// ---------------- causal GQA flash attention, 2-way split-KV, 128-row q-tiles -------
__global__ __launch_bounds__(512)
void attn_kernel(const unsigned short* __restrict__ Q, const unsigned short* __restrict__ K,
                 const unsigned short* __restrict__ V, unsigned short* __restrict__ Opart,
                 float* __restrict__ ML) {
    const int hf = blockIdx.y;
    const int hd = blockIdx.z;
    const int kvh = hd >> 2;
    const int tid = threadIdx.x, wv = tid >> 6, lane = tid & 63;
    const int lr = lane & 15, lgp = lane >> 4;

    __shared__ __attribute__((aligned(16))) unsigned short Ks[2][64 * 128];
    __shared__ __attribute__((aligned(16))) unsigned short Vt[128 * 64];

    int koff[2];
#pragma unroll
    for (int j = 0; j < 2; ++j) {
        int a = (wv * 2 + j) * 512 + lane * 8;
        koff[j] = a ^ (((a >> 7) & 7) << 3);
    }
    const int vpos = ((lane >> 2) & 3) * 16 + (lane >> 4) * 4 + (lane & 3);
    const unsigned short* Kg = K + (size_t)kvh * S_LEN * HDIM;
    const unsigned short* Vg = V + (size_t)kvh * S_LEN * HDIM;

    auto stageK = [&](int buf, int kb) {
        const unsigned short* kg = Kg + (size_t)kb * 64 * HDIM;
#pragma unroll
        for (int j = 0; j < 2; ++j) {
            __builtin_amdgcn_global_load_lds(
                (const __attribute__((address_space(1))) void*)(kg + koff[j]),
                (__attribute__((address_space(3))) void*)&Ks[buf][(wv * 2 + j) * 512], 16, 0, 0);
        }
    };

#pragma unroll 1
    for (int rep = 0; rep < 2; ++rep) {
        const int qt = rep ? (15 - (int)blockIdx.x) : (int)blockIdx.x;  // 128-row tile
        const int qg = qt * 128 + wv * 16 + lr;
        const int n = 2 * qt + 2, mid = qt + 1;
        const int s = hf ? mid : 0, e = hf ? n : mid;

        __syncthreads();   // LDS reuse guard across reps

        short8 aq[4];
        {
            const unsigned short* qp = Q + ((size_t)hd * S_LEN + qg) * HDIM + lgp * 8;
#pragma unroll
            for (int kk = 0; kk < 4; ++kk) aq[kk] = *(const short8*)(qp + kk * 32);
        }

        f32x4 oacc[8] = {};
        float m_i = -3.0e38f, l_i = 0.f;

        short8 vcur[2];
        if (s < e) {
            stageK(s & 1, s);
            const unsigned short* vp = Vg + (size_t)s * 64 * HDIM + lane * HDIM + wv * 16;
#pragma unroll
            for (int r2 = 0; r2 < 2; ++r2) vcur[r2] = *(const short8*)(vp + r2 * 8);
        }

#pragma unroll 1
        for (int kb = s; kb < e; ++kb) {
            const int cur = kb & 1;
            __syncthreads();   // b1: drains prev-iter stage + V loads; prev PV done

            if (kb + 1 < e) stageK(cur ^ 1, kb + 1);
#pragma unroll
            for (int r2 = 0; r2 < 2; ++r2) {
#pragma unroll
                for (int en = 0; en < 8; ++en) {
                    int d = wv * 16 + r2 * 8 + en;
                    Vt[(d * 64 + vpos) ^ ((d & 7) << 3)] = ((const unsigned short*)&vcur[r2])[en];
                }
            }
            if (kb + 1 < e) {
                const unsigned short* vp = Vg + (size_t)(kb + 1) * 64 * HDIM + lane * HDIM + wv * 16;
#pragma unroll
                for (int r2 = 0; r2 < 2; ++r2) vcur[r2] = *(const short8*)(vp + r2 * 8);
            }

            __builtin_amdgcn_s_setprio(1);
            f32x4 sc[4];
#pragma unroll
            for (int nt2 = 0; nt2 < 4; ++nt2) {
                f32x4 a = {};
                const int krow = nt2 * 16 + lr;
                const int swz = (krow & 7) << 3;
#pragma unroll
                for (int kk = 0; kk < 4; ++kk) {
                    short8 ak = *(const short8*)&Ks[cur][(krow * 128 + kk * 32 + lgp * 8) ^ swz];
                    a = __builtin_amdgcn_mfma_f32_16x16x32_bf16(ak, aq[kk], a, 0, 0, 0);
                }
                sc[nt2] = a;
            }
            __builtin_amdgcn_s_setprio(0);

            if (kb >= 2 * qt) {   // diagonal kv tiles of this 128-row q-tile
#pragma unroll
                for (int nt2 = 0; nt2 < 4; ++nt2)
#pragma unroll
                    for (int i = 0; i < 4; ++i) {
                        int kvg = kb * 64 + nt2 * 16 + 4 * lgp + i;
                        if (kvg > qg) sc[nt2][i] = -1.0e30f;
                    }
            }

            float vmax = fmaxf(fmaxf(fmaxf(sc[0][0], sc[0][1]), fmaxf(sc[0][2], sc[0][3])),
                               fmaxf(fmaxf(sc[1][0], sc[1][1]), fmaxf(sc[1][2], sc[1][3])));
            vmax = fmaxf(vmax, fmaxf(fmaxf(fmaxf(sc[2][0], sc[2][1]), fmaxf(sc[2][2], sc[2][3])),
                                     fmaxf(fmaxf(sc[3][0], sc[3][1]), fmaxf(sc[3][2], sc[3][3]))));
            vmax = fmaxf(vmax, __shfl_xor(vmax, 16));
            vmax = fmaxf(vmax, __shfl_xor(vmax, 32));

            if (!__all(vmax <= m_i + 11.0f)) {   // defer-max: P bounded by 2^11
                float mn = fmaxf(m_i, vmax);
                float fe = __builtin_amdgcn_exp2f(m_i - mn);
                m_i = mn;
                l_i *= fe;
                float feb[4];
#pragma unroll
                for (int i2 = 0; i2 < 4; ++i2) feb[i2] = __shfl(fe, 4 * lgp + i2);
#pragma unroll
                for (int t = 0; t < 8; ++t)
#pragma unroll
                    for (int i2 = 0; i2 < 4; ++i2) oacc[t][i2] *= feb[i2];
            }

            float rs = 0.f;
#pragma unroll
            for (int nt2 = 0; nt2 < 4; ++nt2)
#pragma unroll
                for (int i = 0; i < 4; ++i) {
                    float pv = __builtin_amdgcn_exp2f(sc[nt2][i] - m_i);
                    sc[nt2][i] = pv;
                    rs += pv;
                }
            rs += __shfl_xor(rs, 16);
            rs += __shfl_xor(rs, 32);
            l_i += rs;

            union { unsigned u[4]; short8 sv; } a0, a1;
            a0.u[0] = cvt_pk_bf16(sc[0][0], sc[0][1]);
            a0.u[1] = cvt_pk_bf16(sc[0][2], sc[0][3]);
            a0.u[2] = cvt_pk_bf16(sc[1][0], sc[1][1]);
            a0.u[3] = cvt_pk_bf16(sc[1][2], sc[1][3]);
            a1.u[0] = cvt_pk_bf16(sc[2][0], sc[2][1]);
            a1.u[1] = cvt_pk_bf16(sc[2][2], sc[2][3]);
            a1.u[2] = cvt_pk_bf16(sc[3][0], sc[3][1]);
            a1.u[3] = cvt_pk_bf16(sc[3][2], sc[3][3]);

            // b2: scatter visibility only — NO vmcnt drain (staging keeps flying)
            asm volatile("s_waitcnt lgkmcnt(0)" ::: "memory");
            __builtin_amdgcn_sched_barrier(0);
            __builtin_amdgcn_s_barrier();

            __builtin_amdgcn_s_setprio(1);
#pragma unroll
            for (int t = 0; t < 8; ++t) {
                const int d = t * 16 + lr;
                const int swz = (d & 7) << 3;
                const int dbase = d * 64 + lgp * 16;
                short8 bv0 = *(const short8*)&Vt[(dbase) ^ swz];
                short8 bv1 = *(const short8*)&Vt[(dbase + 8) ^ swz];
                oacc[t] = __builtin_amdgcn_mfma_f32_16x16x32_bf16(a0.sv, bv0, oacc[t], 0, 0, 0);
                oacc[t] = __builtin_amdgcn_mfma_f32_16x16x32_bf16(a1.sv, bv1, oacc[t], 0, 0, 0);
            }
            __builtin_amdgcn_s_setprio(0);
        }

        unsigned short* op = Opart + ((size_t)hf * S_LEN + qt * 128 + wv * 16 + 4 * lgp) * HID
                           + hd * HDIM + lr;
#pragma unroll
        for (int t = 0; t < 8; ++t)
#pragma unroll
            for (int i2 = 0; i2 < 4; ++i2)
                op[(size_t)i2 * HID + t * 16] = f2bf(oacc[t][i2]);
        if (lgp == 0) {
            float2* mlp = (float2*)ML;
            mlp[((size_t)hf * S_LEN + qt * 128 + wv * 16 + lr) * NHEAD + hd] =
                make_float2(m_i, l_i);
        }
    }
}

// ---------------- launch ----------------
extern "C" void kernel_launch(void* const* d_in, const int* in_sizes, int n_in,
                              void* d_out, int out_size, void* d_ws, size_t ws_size,
                              hipStream_t stream) {
    const float* hidden = (const float*)d_in[0];
    const int*   pos    = (const int*)d_in[1];
    const float* su_qkv = (const float*)d_in[2];
    const float* su_o   = (const float*)d_in[3];
    const float* ws_qkv = (const float*)d_in[4];
    const float* ws_o   = (const float*)d_in[5];
    const float* Wq     = (const float*)d_in[6];
    const float* Wk     = (const float*)d_in[7];
    const float* Wv     = (const float*)d_in[8];
    const float* Wo     = (const float*)d_in[9];
    float* out = (float*)d_out;

    char* ws = (char*)d_ws;
    unsigned short* Wcat = (unsigned short*)(ws);                        // [6144][4096] bf16
    unsigned short* Wob  = (unsigned short*)(ws + 50331648);             // [4096][4096] bf16
    unsigned short* xb   = (unsigned short*)(ws + 83886080);             // [2048][4096] bf16
    unsigned short* Opart= (unsigned short*)(ws + 100663296);            // [2][2048][4096] bf16
    float*          ML   = (float*)(ws + 134217728);                     // [2][2048][32][2] f32
    unsigned short* Qb   = (unsigned short*)(ws + 150994944);            // [32][2048][128] bf16
    unsigned short* Kb   = Qb + (size_t)NHEAD * S_LEN * HDIM;
    unsigned short* Vb   = Kb + (size_t)NKVH * S_LEN * HDIM;

    prep_kernel<<<4608, 256, 0, stream>>>(hidden, su_qkv, ws_qkv, ws_o,
                                          Wq, Wk, Wv, Wo, xb, Wcat, Wob);
    gemm_qkv<<<dim3(NQKV / 128, S_LEN / 128), 256, 0, stream>>>(xb, Wcat, pos, Qb, Kb, Vb);
    attn_kernel<<<dim3(8, 2, NHEAD), 512, 0, stream>>>(Qb, Kb, Vb, Opart, ML);
    fwht_merge<<<S_LEN, 256, 0, stream>>>(Opart, ML, su_o, xb);
    gemm_bt<<<dim3(HID / 128, S_LEN / 128), 256, 0, stream>>>(xb, Wob, out, S_LEN, HID, HID);
}